// Round 8
// baseline (1866.455 us; speedup 1.0000x reference)
//
#include <hip/hip_runtime.h>

// GCN: 2x GCNConv + linear scorer. N=100000, F_IN=128, H=32, E=3.2M.
// Round 8: hierarchical CSR build. Round-7 counters: fill_kernel 292us,
// WRITE_SIZE 196MB (scattered 4B csr writes -> 64B line write-through, 100k
// active tails thrash L2). Fix: bin edges into 782 buckets of 128 dst rows
// (appending writes, 782 active lines -> write-combines), then per-bucket
// LDS hist+scan+fill (csr writes land in a ~16KB L2-resident slice).
// This also eliminates the 100k-bin global hist and the global scan chain.

constexpr int NN  = 100000;
constexpr int FIN = 128;
constexpr int H   = 32;
constexpr int BSH = 7;                    // bucket shift: 128 rows/bucket
constexpr int BRW = 1 << BSH;             // 128
constexpr int NB  = (NN + BRW - 1) >> BSH; // 782 buckets

__global__ void zero_small_kernel(int* __restrict__ p, int n) {
  int i = threadIdx.x;
  if (i < n) p[i] = 0;
}

// bkcnt[dst>>7] += 1. 3.2M atomics on 3KB table -> L2-trivial.
__global__ void bucket_hist_kernel(const int* __restrict__ dst, int* __restrict__ bkcnt, int E) {
  int stride = gridDim.x * blockDim.x;
  for (int e = blockIdx.x * blockDim.x + threadIdx.x; e < E; e += stride)
    atomicAdd(&bkcnt[dst[e] >> BSH], 1);
}

// Exclusive scan of bkcnt[NB] -> bkcur (single block, Hillis-Steele over 1024).
__global__ void bucket_scan_kernel(const int* __restrict__ bkcnt, int* __restrict__ bkcur, int nb) {
  __shared__ int sm[2][1024];
  int tid = threadIdx.x;
  int v = (tid < nb) ? bkcnt[tid] : 0;
  sm[0][tid] = v;
  __syncthreads();
  int cur = 0;
  #pragma unroll
  for (int off = 1; off < 1024; off <<= 1) {
    int a = sm[cur][tid];
    if (tid >= off) a += sm[cur][tid - off];
    sm[cur ^ 1][tid] = a;
    cur ^= 1;
    __syncthreads();
  }
  if (tid < nb) bkcur[tid] = sm[cur][tid] - v;   // exclusive offsets
}

// Append (src,dst) to the dst's bucket region. After this kernel bkcur[b] ==
// end of region b (== start of region b+1).
__global__ void bin_kernel(const int* __restrict__ src, const int* __restrict__ dst,
                           int* __restrict__ bkcur, int2* __restrict__ tmp, int E) {
  int stride = gridDim.x * blockDim.x;
  for (int e = blockIdx.x * blockDim.x + threadIdx.x; e += 0, e < E; e += stride) {
    int d = dst[e];
    int pos = atomicAdd(&bkcur[d >> BSH], 1);
    tmp[pos] = make_int2(src[e], d);
  }
}

// One block per bucket: LDS hist -> cnt/dinv, LDS scan -> row_start,
// LDS-cursor fill -> csr. All global writes dense / L2-slice-resident.
__global__ void finalize_kernel(const int2* __restrict__ tmp, const int* __restrict__ bkcur,
                                int* __restrict__ cnt, int* __restrict__ row_start,
                                float* __restrict__ dinv, int* __restrict__ csr, int n) {
  __shared__ int lcnt[BRW];
  __shared__ int lscan[2][BRW];
  __shared__ int lcur[BRW];
  int b = blockIdx.x;
  int tid = threadIdx.x;
  int t0 = b ? bkcur[b - 1] : 0;
  int t1 = bkcur[b];
  int r0 = b << BSH;
  int nr = min(BRW, n - r0);

  if (tid < BRW) lcnt[tid] = 0;
  __syncthreads();
  for (int e = t0 + tid; e < t1; e += blockDim.x)
    atomicAdd(&lcnt[tmp[e].y - r0], 1);
  __syncthreads();

  // exclusive scan over BRW=128 (threads < 128 participate)
  int cur = 0;
  if (tid < BRW) lscan[0][tid] = lcnt[tid];
  __syncthreads();
  #pragma unroll
  for (int off = 1; off < BRW; off <<= 1) {
    if (tid < BRW) {
      int a = lscan[cur][tid];
      if (tid >= off) a += lscan[cur][tid - off];
      lscan[cur ^ 1][tid] = a;
    }
    cur ^= 1;
    __syncthreads();
  }
  if (tid < nr) {
    int c = lcnt[tid];
    int start = t0 + lscan[cur][tid] - c;   // exclusive + bucket base
    cnt[r0 + tid] = c;
    row_start[r0 + tid] = start;
    dinv[r0 + tid] = rsqrtf((float)c + 1.0f);
    lcur[tid] = start;
  }
  __syncthreads();

  for (int e = t0 + tid; e < t1; e += blockDim.x) {
    int2 p = tmp[e];
    int pos = atomicAdd(&lcur[p.y - r0], 1);
    csr[pos] = p.x;
  }
}

// h[i][j] = sum_k x[i][k] * W[k][j]   (K=128, J=32). One thread per output;
// 32 consecutive lanes share one x row; W staged in LDS.
__global__ void gemm1_kernel(const float* __restrict__ x, const float* __restrict__ W,
                             float* __restrict__ h, int n) {
  __shared__ float Wl[FIN * H];
  for (int t = threadIdx.x; t < FIN * H; t += blockDim.x) Wl[t] = W[t];
  __syncthreads();
  int t = blockIdx.x * blockDim.x + threadIdx.x;
  int i = t >> 5, j = t & 31;
  if (i >= n) return;
  const float4* xr = (const float4*)(x + (size_t)i * FIN);
  float acc = 0.f;
  #pragma unroll 8
  for (int k4 = 0; k4 < FIN / 4; ++k4) {
    float4 v = xr[k4];
    acc += v.x * Wl[(k4 * 4 + 0) * H + j];
    acc += v.y * Wl[(k4 * 4 + 1) * H + j];
    acc += v.z * Wl[(k4 * 4 + 2) * H + j];
    acc += v.w * Wl[(k4 * 4 + 3) * H + j];
  }
  h[t] = acc;
}

// h2[i][j] = sum_k a[i][k] * W[k][j]   (K=32, J=32)
__global__ void gemm2_kernel(const float* __restrict__ a, const float* __restrict__ W,
                             float* __restrict__ h, int n) {
  __shared__ float Wl[H * H];
  for (int t = threadIdx.x; t < H * H; t += blockDim.x) Wl[t] = W[t];
  __syncthreads();
  int t = blockIdx.x * blockDim.x + threadIdx.x;
  int i = t >> 5, j = t & 31;
  if (i >= n) return;
  const float4* ar = (const float4*)(a + (size_t)i * H);
  float acc = 0.f;
  #pragma unroll
  for (int k4 = 0; k4 < H / 4; ++k4) {
    float4 v = ar[k4];
    acc += v.x * Wl[(k4 * 4 + 0) * H + j];
    acc += v.y * Wl[(k4 * 4 + 1) * H + j];
    acc += v.z * Wl[(k4 * 4 + 2) * H + j];
    acc += v.w * Wl[(k4 * 4 + 3) * H + j];
  }
  h[t] = acc;
}

// Row-gather aggregation: 32-lane group per dst row r, lane j = feature.
__global__ void gather1_kernel(const int* __restrict__ csr, const int* __restrict__ cnt,
                               const int* __restrict__ rstart, const float* __restrict__ dinv,
                               const float* __restrict__ h, const float* __restrict__ b,
                               float* __restrict__ a1, int n) {
  int t = blockIdx.x * blockDim.x + threadIdx.x;
  int r = t >> 5, j = t & 31;
  if (r >= n) return;
  int k = rstart[r];
  int end = k + cnt[r];
  float acc = 0.f;
  for (; k + 4 <= end; k += 4) {
    int s0 = csr[k], s1 = csr[k + 1], s2 = csr[k + 2], s3 = csr[k + 3];
    float v0 = h[s0 * H + j], v1 = h[s1 * H + j], v2 = h[s2 * H + j], v3 = h[s3 * H + j];
    acc += v0 * dinv[s0]; acc += v1 * dinv[s1];
    acc += v2 * dinv[s2]; acc += v3 * dinv[s3];
  }
  for (; k < end; ++k) { int s = csr[k]; acc += h[s * H + j] * dinv[s]; }
  float di = dinv[r];
  float v = acc * di + h[t] * di * di + b[j];   // t == r*H+j
  a1[t] = fmaxf(v, 0.f);
}

// Same gather over h2, fused with the FC scorer.
__global__ void gather2_kernel(const int* __restrict__ csr, const int* __restrict__ cnt,
                               const int* __restrict__ rstart, const float* __restrict__ dinv,
                               const float* __restrict__ h2, const float* __restrict__ b2,
                               const float* __restrict__ Wfc, const float* __restrict__ bfc,
                               float* __restrict__ out, int n) {
  int t = blockIdx.x * blockDim.x + threadIdx.x;
  int r = t >> 5, j = t & 31;
  if (r >= n) return;
  int k = rstart[r];
  int end = k + cnt[r];
  float acc = 0.f;
  for (; k + 4 <= end; k += 4) {
    int s0 = csr[k], s1 = csr[k + 1], s2 = csr[k + 2], s3 = csr[k + 3];
    float v0 = h2[s0 * H + j], v1 = h2[s1 * H + j], v2 = h2[s2 * H + j], v3 = h2[s3 * H + j];
    acc += v0 * dinv[s0]; acc += v1 * dinv[s1];
    acc += v2 * dinv[s2]; acc += v3 * dinv[s3];
  }
  for (; k < end; ++k) { int s = csr[k]; acc += h2[s * H + j] * dinv[s]; }
  float di = dinv[r];
  float v = acc * di + h2[t] * di * di + b2[j];
  v = fmaxf(v, 0.f) * Wfc[j];
  #pragma unroll
  for (int m = 16; m; m >>= 1) v += __shfl_xor(v, m, 32);
  if (j == 0) out[r] = v + bfc[0];
}

extern "C" void kernel_launch(void* const* d_in, const int* in_sizes, int n_in,
                              void* d_out, int out_size, void* d_ws, size_t ws_size,
                              hipStream_t stream) {
  const float* x   = (const float*)d_in[0];
  const int*   ei  = (const int*)d_in[1];
  const float* W1  = (const float*)d_in[2];
  const float* b1  = (const float*)d_in[3];
  const float* W2  = (const float*)d_in[4];
  const float* b2  = (const float*)d_in[5];
  const float* Wfc = (const float*)d_in[6];
  const float* bfc = (const float*)d_in[7];
  float* out = (float*)d_out;

  const int E = in_sizes[1] / 2;
  const int* src = ei;
  const int* dst = ei + E;

  // ws layout (39.6 MB, same footprint as round 7):
  // [csr E int | cnt N int | row_start N int | dinv N f32 | h N*H f32 | a1 N*H f32]
  // tmp (E int2 = 25.6MB) aliases h+a1 (dead until gemm1, which runs after finalize).
  char* w = (char*)d_ws;
  int*   csr       = (int*)w;                    w += (size_t)E * 4;
  int*   cnt       = (int*)w;                    w += (size_t)NN * 4;
  int*   row_start = (int*)w;                    w += (size_t)NN * 4;
  float* dinv      = (float*)w;                  w += (size_t)NN * 4;
  float* h         = (float*)w;
  int2*  tmp       = (int2*)h;
  float* a1        = h + (size_t)NN * H;

  // Bucket counters live in d_out (400KB, only written by gather2 at the end).
  int* bkcnt = (int*)d_out;
  int* bkcur = (int*)d_out + 1024;

  const int nb_nh = (NN * H + 255) / 256;

  zero_small_kernel<<<1, 1024, 0, stream>>>(bkcnt, NB);
  bucket_hist_kernel<<<2048, 256, 0, stream>>>(dst, bkcnt, E);
  bucket_scan_kernel<<<1, 1024, 0, stream>>>(bkcnt, bkcur, NB);
  bin_kernel<<<2048, 256, 0, stream>>>(src, dst, bkcur, tmp, E);
  finalize_kernel<<<NB, 256, 0, stream>>>(tmp, bkcur, cnt, row_start, dinv, csr, NN);
  gemm1_kernel<<<nb_nh, 256, 0, stream>>>(x, W1, h, NN);
  gather1_kernel<<<nb_nh, 256, 0, stream>>>(csr, cnt, row_start, dinv, h, b1, a1, NN);
  gemm2_kernel<<<nb_nh, 256, 0, stream>>>(a1, W2, h, NN);  // h := h2
  gather2_kernel<<<nb_nh, 256, 0, stream>>>(csr, cnt, row_start, dinv, h, b2, Wfc, bfc, out, NN);
}